// Round 19
// baseline (125.810 us; speedup 1.0000x reference)
//
#include <hip/hip_runtime.h>

enum { B_ = 32, T_ = 1024, V_ = 512, S_ = 128 };

static constexpr float K2   = 1.4426950408889634f;  // 1/ln2
static constexpr float LN2F = 0.6931471805599453f;
#define BOOSTI 6

typedef float f32x4 __attribute__((ext_vector_type(4)));
#define AS3 __attribute__((address_space(3)))

#define DPPI(x, ctrl) __builtin_amdgcn_update_dpp(0, (x), (ctrl), 0xF, 0xF, true)
#define DPPF(x, ctrl) __int_as_float(DPPI(__float_as_int(x), (ctrl)))
#define DPP_WSR1(x) DPPF((x), 0x138)   // lane l <- lane l-1, lane 0 <- 0

__device__ __forceinline__ float dpp_wave_max_l63(float x) {
  x = fmaxf(x, DPPF(x, 0xB1));   x = fmaxf(x, DPPF(x, 0x4E));
  x = fmaxf(x, DPPF(x, 0x124));  x = fmaxf(x, DPPF(x, 0x128));
  x = fmaxf(x, DPPF(x, 0x142));  x = fmaxf(x, DPPF(x, 0x143));
  return x;
}
// butterfly sum: xor1, xor2 (quad sums), ror4+ror8 (row16 sums), bcast15/31.
// Total valid in lane 63.
#define DPP_SUM63(x) { \
  x += DPPF(x, 0xB1);  x += DPPF(x, 0x4E);  x += DPPF(x, 0x124); \
  x += DPPF(x, 0x128); x += DPPF(x, 0x142); x += DPPF(x, 0x143); }

// Fused kernel: 4 waves/block. Wave 0 = DP consumer; waves 1-3 = producers
// that read raw logits, compute lse + masked linear probs, and stage 32-row
// chunks into a 3-buffer LDS ring. No Q-table, no separate prep kernel.
__global__ __launch_bounds__(256, 1) void ctc_fused(
    const float* __restrict__ logits, const int* __restrict__ targets,
    const int* __restrict__ loglen, const int* __restrict__ tgtlen,
    float* __restrict__ out) {
  __shared__ f32x4 buf[3][32 * 64];   // 3 x 32 KiB chunks
  __shared__ int flag_ready[3], flag_done[3];
  __shared__ float A[257];
  const int wv = threadIdx.x >> 6, l = threadIdx.x & 63;
  const int b = blockIdx.x;
  const int len = loglen[b], tl = tgtlen[b];
  const int nch = (len - 1 + 31) >> 5;
  const float* Lb = logits + (size_t)b * T_ * V_;

  const int2 ee = ((const int2*)(targets + b * S_))[l];
  const int e1 = ee.x, e3 = ee.y;
  const int smax = 2 * tl;

  if (threadIdx.x == 0) {
    flag_ready[0] = flag_ready[1] = flag_ready[2] = 0;
    flag_done[0] = flag_done[1] = flag_done[2] = 0;
  }
  __syncthreads();

  if (wv != 0) {
    // ---------------- producers (waves 1..3, chunks round-robin) ----------
    const bool v0m = (4 * l     <= smax);
    const bool v1m = (4 * l + 1 <= smax);
    const bool v2m = (4 * l + 2 <= smax);
    const bool v3m = (4 * l + 3 <= smax);
    const int l16 = l * 16, e1b = e1 * 4, e3b = e3 * 4;

    f32x4 pa0, pa1, pa2, pa3, pc0, pc1, pc2, pc3;
    float g10, g11, g12, g13, g30, g31, g32, g33;

#define PISS(s, ROW) { \
    int rr_ = (ROW) > 1023 ? 1023 : (ROW); int rb_ = rr_ * 2048; \
    asm volatile("global_load_dwordx4 %0, %1, %2" : "=&v"(pa##s) : "v"(rb_ + l16), "s"(Lb)); \
    asm volatile("global_load_dwordx4 %0, %1, %2" : "=&v"(pc##s) : "v"(rb_ + 1024 + l16), "s"(Lb)); \
    asm volatile("global_load_dword %0, %1, %2"   : "=&v"(g1##s) : "v"(rb_ + e1b), "s"(Lb)); \
    asm volatile("global_load_dword %0, %1, %2"   : "=&v"(g3##s) : "v"(rb_ + e3b), "s"(Lb)); }

#define PROW(i, s, VM, DO) { \
    asm volatile("s_waitcnt vmcnt(" #VM ")" \
        : "+v"(pa##s), "+v"(pc##s), "+v"(g1##s), "+v"(g3##s)); \
    float x8_ = __builtin_exp2f(pa##s.x * K2) + __builtin_exp2f(pa##s.y * K2) + \
                __builtin_exp2f(pa##s.z * K2) + __builtin_exp2f(pa##s.w * K2) + \
                __builtin_exp2f(pc##s.x * K2) + __builtin_exp2f(pc##s.y * K2) + \
                __builtin_exp2f(pc##s.z * K2) + __builtin_exp2f(pc##s.w * K2); \
    DPP_SUM63(x8_); \
    const float ss_ = __int_as_float(__builtin_amdgcn_readlane(__float_as_int(x8_), 63)); \
    const float sh_ = (float)BOOSTI - __builtin_log2f(ss_); \
    const float lgb_ = __int_as_float(__builtin_amdgcn_readfirstlane(__float_as_int(pa##s.x))); \
    const float pe1_ = __builtin_exp2f(fmaf(g1##s, K2, sh_)); \
    const float pe3_ = __builtin_exp2f(fmaf(g3##s, K2, sh_)); \
    const float pb_  = __builtin_exp2f(fmaf(lgb_, K2, sh_)); \
    f32x4 qq_; \
    qq_.x = v1m ? pe1_ : 0.0f; qq_.y = v3m ? pe3_ : 0.0f; \
    qq_.z = v0m ? pb_  : 0.0f; qq_.w = v2m ? pb_  : 0.0f; \
    pbuf[(i) * 64 + l] = qq_; \
    if (DO) { PISS(s, r0 + (i) + 4) } }

#define PDRAIN asm volatile("s_waitcnt lgkmcnt(0)" ::: "memory");

    for (int c = wv - 1; c < nch; c += 3) {
      if (c >= 3) {
        while (((volatile int*)flag_done)[c % 3] < c - 2)
          __builtin_amdgcn_s_sleep(1);
      }
      const int r0 = 1 + 32 * c;
      f32x4* pbuf = &buf[c % 3][0];
      PISS(0, r0) PISS(1, r0 + 1) PISS(2, r0 + 2) PISS(3, r0 + 3)
      PROW(0, 0, 12, 1)  PROW(1, 1, 12, 1)  PROW(2, 2, 12, 1)  PROW(3, 3, 12, 1)
      PROW(4, 0, 12, 1)  PROW(5, 1, 12, 1)  PROW(6, 2, 12, 1)  PROW(7, 3, 12, 1)
      PDRAIN
      PROW(8, 0, 12, 1)  PROW(9, 1, 12, 1)  PROW(10, 2, 12, 1) PROW(11, 3, 12, 1)
      PROW(12, 0, 12, 1) PROW(13, 1, 12, 1) PROW(14, 2, 12, 1) PROW(15, 3, 12, 1)
      PDRAIN
      PROW(16, 0, 12, 1) PROW(17, 1, 12, 1) PROW(18, 2, 12, 1) PROW(19, 3, 12, 1)
      PROW(20, 0, 12, 1) PROW(21, 1, 12, 1) PROW(22, 2, 12, 1) PROW(23, 3, 12, 1)
      PDRAIN
      PROW(24, 0, 12, 1) PROW(25, 1, 12, 1) PROW(26, 2, 12, 1) PROW(27, 3, 12, 1)
      PROW(28, 0, 12, 0) PROW(29, 1, 8, 0)  PROW(30, 2, 4, 0)  PROW(31, 3, 0, 0)
      PDRAIN
      if (l == 0) ((volatile int*)flag_ready)[c % 3] = c + 1;
    }
    return;
  }

  // ---------------- consumer (wave 0) ----------------
  const int em1 = __shfl_up(e3, 1);
  const float m1 = ((l > 0) && (e1 != 0) && (e1 != em1)) ? 1.0f : 0.0f;
  const float m3 = ((e3 != 0) && (e3 != e1)) ? 1.0f : 0.0f;
  const float v4l = ((l == 63) && (smax >= 256)) ? 1.0f : 0.0f;

  // t = 0 init from raw logits (same lse sequence as producers)
  const f32x4* R0 = (const f32x4*)Lb;
  f32x4 a0 = R0[l], c0 = R0[l + 64];
  float s0 = __builtin_exp2f(a0.x * K2) + __builtin_exp2f(a0.y * K2) +
             __builtin_exp2f(a0.z * K2) + __builtin_exp2f(a0.w * K2) +
             __builtin_exp2f(c0.x * K2) + __builtin_exp2f(c0.y * K2) +
             __builtin_exp2f(c0.z * K2) + __builtin_exp2f(c0.w * K2);
  DPP_SUM63(s0);
  const float ss0 = __int_as_float(__builtin_amdgcn_readlane(__float_as_int(s0), 63));
  const float sh0 = (float)BOOSTI - __builtin_log2f(ss0);
  const float lgb0 = __int_as_float(__builtin_amdgcn_readfirstlane(__float_as_int(a0.x)));
  const float lg10 = Lb[targets[b * S_]];      // lane-0 label logit (uniform)
  float p0 = (l == 0) ? __builtin_exp2f(fmaf(lgb0, K2, sh0)) : 0.0f;
  float p1 = (l == 0) ? __builtin_exp2f(fmaf(lg10, K2, sh0)) : 0.0f;
  float p2 = 0.0f, p3 = 0.0f, p4 = 0.0f;

  const unsigned bufbase = (unsigned)(uintptr_t)(AS3 char*)(void*)&buf[0][0];
  asm volatile("s_waitcnt vmcnt(0) lgkmcnt(0)" ::: "memory");

  f32x4 q0, q1, q2, q3, q4, q5, q6, q7;
#define DSRO(R, O) asm volatile("ds_read_b128 %0, %1 offset:" #O \
      : "=&v"(R) : "v"(vb));
#define WT4(RA, RB, RC, RD, N) asm volatile("s_waitcnt lgkmcnt(" #N ")" \
      : "+v"(RA), "+v"(RB), "+v"(RC), "+v"(RD));
#define WTL(R, N) asm volatile("s_waitcnt lgkmcnt(" #N ")" : "+v"(R));

#define COMPUTE(RX) { \
    const float n1_ = DPP_WSR1(p3); \
    const float w0_ = (p0 + n1_) * RX.z; \
    const float w1_ = (p0 + p1 + n1_ * m1) * RX.x; \
    const float w2_ = (p1 + p2) * RX.w; \
    const float w3_ = (p2 + p3 + p1 * m3) * RX.y; \
    const float w4_ = (p4 + p3) * RX.w * v4l; \
    p0 = w0_; p1 = w1_; p2 = w2_; p3 = w3_; p4 = w4_; \
  }
#define RENORM { \
    float m_ = fmaxf(fmaxf(fmaxf(p0, p1), fmaxf(p2, p3)), p4); \
    m_ = dpp_wave_max_l63(m_); \
    const int wm_ = __builtin_amdgcn_readlane(__float_as_int(m_), 63); \
    const int e_ = (wm_ >> 23) & 0xFF; \
    const float sc_ = __int_as_float((254 - e_) << 23); \
    p0 *= sc_; p1 *= sc_; p2 *= sc_; p3 *= sc_; p4 *= sc_; \
    shift += e_ - 127; \
  }
#define CD(R, O) { COMPUTE(R); DSRO(R, O); }
#define TS(R, O, i) { WTL(R, 7); if (t0 + (i) < len) COMPUTE(R); DSRO(R, O); }
#define TD(R, N, i) { WTL(R, N); if (t0 + (i) < len) COMPUTE(R); }

  int shift = 0;
  for (int c = 0; c < nch; ++c) {
    const int t0 = 1 + 32 * c;
    while (((volatile int*)flag_ready)[c % 3] < c + 1)
      __builtin_amdgcn_s_sleep(1);
    const unsigned vb = bufbase + (unsigned)(c % 3) * 32768u + (unsigned)l * 16u;

    DSRO(q0, 0)    DSRO(q1, 1024) DSRO(q2, 2048) DSRO(q3, 3072)
    DSRO(q4, 4096) DSRO(q5, 5120) DSRO(q6, 6144) DSRO(q7, 7168)

    if (t0 + 31 < len) {
      WT4(q0, q1, q2, q3, 4) CD(q0, 8192)  CD(q1, 9216)  CD(q2, 10240) CD(q3, 11264)
      WT4(q4, q5, q6, q7, 4) CD(q4, 12288) CD(q5, 13312) CD(q6, 14336) CD(q7, 15360)
      WT4(q0, q1, q2, q3, 4) CD(q0, 16384) CD(q1, 17408) CD(q2, 18432) CD(q3, 19456)
      WT4(q4, q5, q6, q7, 4) CD(q4, 20480) CD(q5, 21504) CD(q6, 22528) CD(q7, 23552)
      RENORM
      WT4(q0, q1, q2, q3, 4) CD(q0, 24576) CD(q1, 25600) CD(q2, 26624) CD(q3, 27648)
      WT4(q4, q5, q6, q7, 4) CD(q4, 28672) CD(q5, 29696) CD(q6, 30720) CD(q7, 31744)
      WT4(q0, q1, q2, q3, 4) COMPUTE(q0) COMPUTE(q1) COMPUTE(q2) COMPUTE(q3)
      WT4(q4, q5, q6, q7, 0) COMPUTE(q4) COMPUTE(q5) COMPUTE(q6) COMPUTE(q7)
      RENORM
    } else {
      TS(q0, 8192, 0)   TS(q1, 9216, 1)   TS(q2, 10240, 2)  TS(q3, 11264, 3)
      TS(q4, 12288, 4)  TS(q5, 13312, 5)  TS(q6, 14336, 6)  TS(q7, 15360, 7)
      TS(q0, 16384, 8)  TS(q1, 17408, 9)  TS(q2, 18432, 10) TS(q3, 19456, 11)
      TS(q4, 20480, 12) TS(q5, 21504, 13) TS(q6, 22528, 14) TS(q7, 23552, 15)
      TS(q0, 24576, 16) TS(q1, 25600, 17) TS(q2, 26624, 18) TS(q3, 27648, 19)
      TS(q4, 28672, 20) TS(q5, 29696, 21) TS(q6, 30720, 22) TS(q7, 31744, 23)
      TD(q0, 7, 24) TD(q1, 6, 25) TD(q2, 5, 26) TD(q3, 4, 27)
      TD(q4, 3, 28) TD(q5, 2, 29) TD(q6, 1, 30) TD(q7, 0, 31)
    }

    asm volatile("s_waitcnt lgkmcnt(0)" ::: "memory");
    if (l == 0) ((volatile int*)flag_done)[c % 3] = c + 1;
  }

  A[4 * l + 0] = p0; A[4 * l + 1] = p1;
  A[4 * l + 2] = p2; A[4 * l + 3] = p3;
  if (l == 63) A[256] = p4;
  asm volatile("s_waitcnt lgkmcnt(0)" ::: "memory");
  if (l == 0) {
    const int ib = 2 * tl;
    const int il = (ib - 1) > 0 ? ib - 1 : 0;
    const float ab = A[ib];
    const float al = (tl > 0) ? A[il] : 0.0f;
    out[b] = -(__builtin_log2f(ab + al) + (float)(shift - BOOSTI * len)) * LN2F;
  }
}

extern "C" void kernel_launch(void* const* d_in, const int* in_sizes, int n_in,
                              void* d_out, int out_size, void* d_ws, size_t ws_size,
                              hipStream_t stream) {
  const float* logits  = (const float*)d_in[0];
  const int*   targets = (const int*)d_in[1];
  const int*   loglen  = (const int*)d_in[2];
  const int*   tgtlen  = (const int*)d_in[3];
  float* out = (float*)d_out;
  ctc_fused<<<B_, 256, 0, stream>>>(logits, targets, loglen, tgtlen, out);
}

// Round 20
// 62.595 us; speedup vs baseline: 2.0099x; 2.0099x over previous
//
#include <hip/hip_runtime.h>

enum { B_ = 32, T_ = 1024, V_ = 512, S_ = 128 };

static constexpr float K2   = 1.4426950408889634f;  // 1/ln2
static constexpr float LN2F = 0.6931471805599453f;
#define BOOSTI 6

typedef float f32x4 __attribute__((ext_vector_type(4)));
#define AS1 __attribute__((address_space(1)))
#define AS3 __attribute__((address_space(3)))

#define DPPI(x, ctrl) __builtin_amdgcn_update_dpp(0, (x), (ctrl), 0xF, 0xF, true)
#define DPPF(x, ctrl) __int_as_float(DPPI(__float_as_int(x), (ctrl)))
#define DPP_WSR1(x) DPPF((x), 0x138)   // lane l <- lane l-1, lane 0 <- 0

__device__ __forceinline__ float dpp_wave_max_l63(float x) {
  x = fmaxf(x, DPPF(x, 0xB1));   x = fmaxf(x, DPPF(x, 0x4E));
  x = fmaxf(x, DPPF(x, 0x124));  x = fmaxf(x, DPPF(x, 0x128));
  x = fmaxf(x, DPPF(x, 0x142));  x = fmaxf(x, DPPF(x, 0x143));
  return x;
}

// Kernel A: per (b,t) fused logsumexp + masked linear-prob table.
// Q[b][t][lane] = (pe1*v1, pe3*v3, pb*v0, pb*v2); row = 64 f32x4 = 1024 B.
// Rows with t >= len[b] are never consumed by the DP (guarded) -> skip them.
__global__ __launch_bounds__(256) void ctc_pre4(
    const float* __restrict__ logits, const int* __restrict__ targets,
    const int* __restrict__ loglen, const int* __restrict__ tgtlen,
    f32x4* __restrict__ Q) {
  const int w = threadIdx.x >> 6, l = threadIdx.x & 63;
  const int row = blockIdx.x * 4 + w;          // row = b*T + t
  const int b = row >> 10;
  const int t = row & (T_ - 1);
  if (t >= loglen[b]) return;                  // dead row: never consumed
  const float* lrow = logits + (size_t)row * V_;
  const float4* r4 = (const float4*)lrow;
  float4 a = r4[l], c = r4[l + 64];
  float s = __builtin_exp2f(a.x * K2) + __builtin_exp2f(a.y * K2) +
            __builtin_exp2f(a.z * K2) + __builtin_exp2f(a.w * K2) +
            __builtin_exp2f(c.x * K2) + __builtin_exp2f(c.y * K2) +
            __builtin_exp2f(c.z * K2) + __builtin_exp2f(c.w * K2);
  #pragma unroll
  for (int off = 32; off; off >>= 1) s += __shfl_xor(s, off, 64);
  const float sh = (float)BOOSTI - __builtin_log2f(s);

  const int2 ee = ((const int2*)(targets + b * S_))[l];
  const int tl = tgtlen[b];
  const float lgb = __shfl(a.x, 0, 64);        // blank logit (elem 0)
  const float lg1 = lrow[ee.x];
  const float lg3 = lrow[ee.y];
  const float pb  = __builtin_exp2f(fmaf(lgb, K2, sh));
  const float pe1 = __builtin_exp2f(fmaf(lg1, K2, sh));
  const float pe3 = __builtin_exp2f(fmaf(lg3, K2, sh));
  const int smax = 2 * tl;
  f32x4 q;
  q.x = (4 * l + 1 <= smax) ? pe1 : 0.0f;
  q.y = (4 * l + 3 <= smax) ? pe3 : 0.0f;
  q.z = (4 * l     <= smax) ? pb  : 0.0f;
  q.w = (4 * l + 2 <= smax) ? pb  : 0.0f;
  Q[(size_t)row * 64 + l] = q;
}

// Kernel B: producer-consumer wave specialization (R17-proven). Wave 1 stages
// 32-row chunks via global_load_lds + vmcnt(0) + flag; wave 0 (s_setprio 1)
// runs the pure {ds_read + lgkm wait + COMPUTE} DP loop.
__global__ __launch_bounds__(128, 1) void ctc_dp7(
    const f32x4* __restrict__ Q, const int* __restrict__ targets,
    const int* __restrict__ loglen, const int* __restrict__ tgtlen,
    float* __restrict__ out) {
  __shared__ f32x4 buf[2][32 * 64];   // 2 x 32 KiB chunks
  __shared__ int flag_ready[2];
  __shared__ int flag_done[2];
  __shared__ float A[257];
  const int wv = threadIdx.x >> 6, l = threadIdx.x & 63;
  const int b = blockIdx.x;
  const int len = loglen[b], tl = tgtlen[b];
  const int nch = (len - 1 + 31) >> 5;
  const f32x4* Qb = Q + (size_t)b * T_ * 64;

  if (threadIdx.x == 0) {
    flag_ready[0] = 0; flag_ready[1] = 0;
    flag_done[0] = 0;  flag_done[1] = 0;
  }
  __syncthreads();

  if (wv == 1) {
    // ---------------- producer ----------------
    for (int c = 0; c < nch; ++c) {
      if (c >= 2) {
        while (((volatile int*)flag_done)[c & 1] < c - 1)
          __builtin_amdgcn_s_sleep(1);
      }
      const int r0 = 1 + 32 * c;
      #pragma unroll
      for (int i = 0; i < 32; ++i) {
        int row = r0 + i; if (row > T_ - 1) row = T_ - 1;
        __builtin_amdgcn_global_load_lds(
            (const AS1 void*)(const void*)(Qb + (size_t)row * 64 + l),
            (AS3 void*)(void*)(&buf[c & 1][i * 64]), 16, 0, 0);
      }
      asm volatile("s_waitcnt vmcnt(0)" ::: "memory");
      if (l == 0) ((volatile int*)flag_ready)[c & 1] = c + 1;
    }
    return;
  }

  // ---------------- consumer (priority-boosted) ----------------
  __builtin_amdgcn_s_setprio(1);

  const int2 ee = ((const int2*)(targets + b * S_))[l];
  const int e1 = ee.x, e3 = ee.y;
  const int em1 = __shfl_up(e3, 1);
  const float m1 = ((l > 0) && (e1 != 0) && (e1 != em1)) ? 1.0f : 0.0f;
  const float m3 = ((e3 != 0) && (e3 != e1)) ? 1.0f : 0.0f;
  const float v4l = ((l == 63) && (2 * tl >= 256)) ? 1.0f : 0.0f;

  f32x4 qi = Qb[l];                    // t = 0 init
  float p0 = (l == 0) ? qi.z : 0.0f;
  float p1 = (l == 0) ? qi.x : 0.0f;
  float p2 = 0.0f, p3 = 0.0f, p4 = 0.0f;

  const unsigned bufbase = (unsigned)(uintptr_t)(AS3 char*)(void*)&buf[0][0];

  f32x4 q0, q1, q2, q3, q4, q5, q6, q7;
#define DSRO(R, O) asm volatile("ds_read_b128 %0, %1 offset:" #O \
      : "=&v"(R) : "v"(vb))
#define WTL(R, N) asm volatile("s_waitcnt lgkmcnt(" #N ")" : "+v"(R))

#define COMPUTE(RX) { \
    const float n1_  = DPP_WSR1(p3); \
    const float w0_ = (p0 + n1_) * RX.z; \
    const float w1_ = (p0 + p1 + n1_ * m1) * RX.x; \
    const float w2_ = (p1 + p2) * RX.w; \
    const float w3_ = (p2 + p3 + p1 * m3) * RX.y; \
    const float w4_ = (p4 + p3) * RX.w * v4l; \
    p0 = w0_; p1 = w1_; p2 = w2_; p3 = w3_; p4 = w4_; \
  }

#define RENORM { \
    float m_ = fmaxf(fmaxf(fmaxf(p0, p1), fmaxf(p2, p3)), p4); \
    m_ = dpp_wave_max_l63(m_); \
    const int wm_ = __builtin_amdgcn_readlane(__float_as_int(m_), 63); \
    const int e_ = (wm_ >> 23) & 0xFF; \
    const float sc_ = __int_as_float((254 - e_) << 23); \
    p0 *= sc_; p1 *= sc_; p2 *= sc_; p3 *= sc_; p4 *= sc_; \
    shift += e_ - 127; \
  }

#define FS(R, O)  { WTL(R, 7); COMPUTE(R); DSRO(R, O); }
#define FD(R, N)  { WTL(R, N); COMPUTE(R); }
#define TS(R, O, i)  { WTL(R, 7); if (t0 + (i) < len) COMPUTE(R); DSRO(R, O); }
#define TD(R, N, i)  { WTL(R, N); if (t0 + (i) < len) COMPUTE(R); }

  int shift = 0;
  for (int c = 0; c < nch; ++c) {
    const int t0 = 1 + 32 * c;
    while (((volatile int*)flag_ready)[c & 1] < c + 1)
      __builtin_amdgcn_s_sleep(1);
    const unsigned vb = bufbase + (unsigned)(c & 1) * 32768u + (unsigned)l * 16u;

    DSRO(q0, 0);    DSRO(q1, 1024); DSRO(q2, 2048); DSRO(q3, 3072);
    DSRO(q4, 4096); DSRO(q5, 5120); DSRO(q6, 6144); DSRO(q7, 7168);

    if (t0 + 31 < len) {
      FS(q0, 8192)  FS(q1, 9216)  FS(q2, 10240) FS(q3, 11264)
      FS(q4, 12288) FS(q5, 13312) FS(q6, 14336) FS(q7, 15360)
      FS(q0, 16384) FS(q1, 17408) FS(q2, 18432) FS(q3, 19456)
      FS(q4, 20480) FS(q5, 21504) FS(q6, 22528) FS(q7, 23552)
      RENORM
      FS(q0, 24576) FS(q1, 25600) FS(q2, 26624) FS(q3, 27648)
      FS(q4, 28672) FS(q5, 29696) FS(q6, 30720) FS(q7, 31744)
      FD(q0, 7) FD(q1, 6) FD(q2, 5) FD(q3, 4)
      FD(q4, 3) FD(q5, 2) FD(q6, 1) FD(q7, 0)
      RENORM
    } else {
      TS(q0, 8192, 0)   TS(q1, 9216, 1)   TS(q2, 10240, 2)  TS(q3, 11264, 3)
      TS(q4, 12288, 4)  TS(q5, 13312, 5)  TS(q6, 14336, 6)  TS(q7, 15360, 7)
      TS(q0, 16384, 8)  TS(q1, 17408, 9)  TS(q2, 18432, 10) TS(q3, 19456, 11)
      TS(q4, 20480, 12) TS(q5, 21504, 13) TS(q6, 22528, 14) TS(q7, 23552, 15)
      TS(q0, 24576, 16) TS(q1, 25600, 17) TS(q2, 26624, 18) TS(q3, 27648, 19)
      TS(q4, 28672, 20) TS(q5, 29696, 21) TS(q6, 30720, 22) TS(q7, 31744, 23)
      TD(q0, 7, 24) TD(q1, 6, 25) TD(q2, 5, 26) TD(q3, 4, 27)
      TD(q4, 3, 28) TD(q5, 2, 29) TD(q6, 1, 30) TD(q7, 0, 31)
    }

    asm volatile("s_waitcnt lgkmcnt(0)" ::: "memory");
    if (l == 0) ((volatile int*)flag_done)[c & 1] = c + 1;
  }

  A[4 * l + 0] = p0; A[4 * l + 1] = p1;
  A[4 * l + 2] = p2; A[4 * l + 3] = p3;
  if (l == 63) A[256] = p4;
  asm volatile("s_waitcnt lgkmcnt(0)" ::: "memory");
  if (l == 0) {
    const int ib = 2 * tl;
    const int il = (ib - 1) > 0 ? ib - 1 : 0;
    const float ab = A[ib];
    const float al = (tl > 0) ? A[il] : 0.0f;
    out[b] = -(__builtin_log2f(ab + al) + (float)(shift - BOOSTI * len)) * LN2F;
  }
}

extern "C" void kernel_launch(void* const* d_in, const int* in_sizes, int n_in,
                              void* d_out, int out_size, void* d_ws, size_t ws_size,
                              hipStream_t stream) {
  const float* logits  = (const float*)d_in[0];
  const int*   targets = (const int*)d_in[1];
  const int*   loglen  = (const int*)d_in[2];
  const int*   tgtlen  = (const int*)d_in[3];
  float* out = (float*)d_out;
  f32x4* Q = (f32x4*)d_ws;   // 32 MiB (proven sufficient in R8-R17)

  ctc_pre4<<<(B_ * T_) / 4, 256, 0, stream>>>(logits, targets, loglen, tgtlen, Q);
  ctc_dp7<<<B_, 128, 0, stream>>>(Q, targets, loglen, tgtlen, out);
}

// Round 21
// 62.241 us; speedup vs baseline: 2.0213x; 1.0057x over previous
//
#include <hip/hip_runtime.h>

enum { B_ = 32, T_ = 1024, V_ = 512, S_ = 128 };

static constexpr float K2   = 1.4426950408889634f;  // 1/ln2
static constexpr float LN2F = 0.6931471805599453f;
#define BOOSTI 6

typedef float f32x4 __attribute__((ext_vector_type(4)));
#define AS1 __attribute__((address_space(1)))
#define AS3 __attribute__((address_space(3)))

#define DPPI(x, ctrl) __builtin_amdgcn_update_dpp(0, (x), (ctrl), 0xF, 0xF, true)
#define DPPF(x, ctrl) __int_as_float(DPPI(__float_as_int(x), (ctrl)))
#define DPP_WSR1(x) DPPF((x), 0x138)   // lane l <- lane l-1, lane 0 <- 0

__device__ __forceinline__ float dpp_wave_max_l63(float x) {
  x = fmaxf(x, DPPF(x, 0xB1));   x = fmaxf(x, DPPF(x, 0x4E));
  x = fmaxf(x, DPPF(x, 0x124));  x = fmaxf(x, DPPF(x, 0x128));
  x = fmaxf(x, DPPF(x, 0x142));  x = fmaxf(x, DPPF(x, 0x143));
  return x;
}

// Kernel A: per (b,t) fused logsumexp + masked linear-prob table.
// Q[b][t][lane] = (pe1*v1, pe3*v3, pb*v0, pb*v2); rows t >= len[b] skipped.
__global__ __launch_bounds__(256) void ctc_pre4(
    const float* __restrict__ logits, const int* __restrict__ targets,
    const int* __restrict__ loglen, const int* __restrict__ tgtlen,
    f32x4* __restrict__ Q) {
  const int w = threadIdx.x >> 6, l = threadIdx.x & 63;
  const int row = blockIdx.x * 4 + w;          // row = b*T + t
  const int b = row >> 10;
  const int t = row & (T_ - 1);
  if (t >= loglen[b]) return;                  // dead row: never consumed
  const float* lrow = logits + (size_t)row * V_;
  const float4* r4 = (const float4*)lrow;
  float4 a = r4[l], c = r4[l + 64];
  float s = __builtin_exp2f(a.x * K2) + __builtin_exp2f(a.y * K2) +
            __builtin_exp2f(a.z * K2) + __builtin_exp2f(a.w * K2) +
            __builtin_exp2f(c.x * K2) + __builtin_exp2f(c.y * K2) +
            __builtin_exp2f(c.z * K2) + __builtin_exp2f(c.w * K2);
  #pragma unroll
  for (int off = 32; off; off >>= 1) s += __shfl_xor(s, off, 64);
  const float sh = (float)BOOSTI - __builtin_log2f(s);

  const int2 ee = ((const int2*)(targets + b * S_))[l];
  const int tl = tgtlen[b];
  const float lgb = __shfl(a.x, 0, 64);        // blank logit (elem 0)
  const float lg1 = lrow[ee.x];
  const float lg3 = lrow[ee.y];
  const float pb  = __builtin_exp2f(fmaf(lgb, K2, sh));
  const float pe1 = __builtin_exp2f(fmaf(lg1, K2, sh));
  const float pe3 = __builtin_exp2f(fmaf(lg3, K2, sh));
  const int smax = 2 * tl;
  f32x4 q;
  q.x = (4 * l + 1 <= smax) ? pe1 : 0.0f;
  q.y = (4 * l + 3 <= smax) ? pe3 : 0.0f;
  q.z = (4 * l     <= smax) ? pb  : 0.0f;
  q.w = (4 * l + 2 <= smax) ? pb  : 0.0f;
  Q[(size_t)row * 64 + l] = q;
}

// Kernel B: producer-consumer (R17/R20-proven) with GROUPED lgkm waits:
// 5 waits per 32-step chunk instead of 32 (each group's 8 reads were issued
// a full group (~900 cy) earlier, so data is resident when the drain runs).
__global__ __launch_bounds__(128, 1) void ctc_dp7(
    const f32x4* __restrict__ Q, const int* __restrict__ targets,
    const int* __restrict__ loglen, const int* __restrict__ tgtlen,
    float* __restrict__ out) {
  __shared__ f32x4 buf[2][32 * 64];   // 2 x 32 KiB chunks
  __shared__ int flag_ready[2];
  __shared__ int flag_done[2];
  __shared__ float A[257];
  const int wv = threadIdx.x >> 6, l = threadIdx.x & 63;
  const int b = blockIdx.x;
  const int len = loglen[b], tl = tgtlen[b];
  const int nch = (len - 1 + 31) >> 5;
  const f32x4* Qb = Q + (size_t)b * T_ * 64;

  if (threadIdx.x == 0) {
    flag_ready[0] = 0; flag_ready[1] = 0;
    flag_done[0] = 0;  flag_done[1] = 0;
  }
  __syncthreads();

  if (wv == 1) {
    // ---------------- producer ----------------
    for (int c = 0; c < nch; ++c) {
      if (c >= 2) {
        while (((volatile int*)flag_done)[c & 1] < c - 1)
          __builtin_amdgcn_s_sleep(1);
      }
      const int r0 = 1 + 32 * c;
      #pragma unroll
      for (int i = 0; i < 32; ++i) {
        int row = r0 + i; if (row > T_ - 1) row = T_ - 1;
        __builtin_amdgcn_global_load_lds(
            (const AS1 void*)(const void*)(Qb + (size_t)row * 64 + l),
            (AS3 void*)(void*)(&buf[c & 1][i * 64]), 16, 0, 0);
      }
      asm volatile("s_waitcnt vmcnt(0)" ::: "memory");
      if (l == 0) ((volatile int*)flag_ready)[c & 1] = c + 1;
    }
    return;
  }

  // ---------------- consumer ----------------
  __builtin_amdgcn_s_setprio(1);

  const int2 ee = ((const int2*)(targets + b * S_))[l];
  const int e1 = ee.x, e3 = ee.y;
  const int em1 = __shfl_up(e3, 1);
  const float m1 = ((l > 0) && (e1 != 0) && (e1 != em1)) ? 1.0f : 0.0f;
  const float m3 = ((e3 != 0) && (e3 != e1)) ? 1.0f : 0.0f;
  const float v4l = ((l == 63) && (2 * tl >= 256)) ? 1.0f : 0.0f;

  f32x4 qi = Qb[l];                    // t = 0 init
  float p0 = (l == 0) ? qi.z : 0.0f;
  float p1 = (l == 0) ? qi.x : 0.0f;
  float p2 = 0.0f, p3 = 0.0f, p4 = 0.0f;

  const unsigned bufbase = (unsigned)(uintptr_t)(AS3 char*)(void*)&buf[0][0];

  f32x4 q0, q1, q2, q3, q4, q5, q6, q7;
#define DSRO(R, O) asm volatile("ds_read_b128 %0, %1 offset:" #O \
      : "=&v"(R) : "v"(vb))
#define WTL(R, N) asm volatile("s_waitcnt lgkmcnt(" #N ")" : "+v"(R))
  // group drain: all 8 queue regs tied so no COMPUTE can hoist above it
#define WAIT8 asm volatile("s_waitcnt lgkmcnt(0)" \
      : "+v"(q0), "+v"(q1), "+v"(q2), "+v"(q3), \
        "+v"(q4), "+v"(q5), "+v"(q6), "+v"(q7))

#define COMPUTE(RX) { \
    const float n1_  = DPP_WSR1(p3); \
    const float w0_ = (p0 + n1_) * RX.z; \
    const float w1_ = (p0 + p1 + n1_ * m1) * RX.x; \
    const float w2_ = (p1 + p2) * RX.w; \
    const float w3_ = (p2 + p3 + p1 * m3) * RX.y; \
    const float w4_ = (p4 + p3) * RX.w * v4l; \
    p0 = w0_; p1 = w1_; p2 = w2_; p3 = w3_; p4 = w4_; \
  }

#define RENORM { \
    float m_ = fmaxf(fmaxf(fmaxf(p0, p1), fmaxf(p2, p3)), p4); \
    m_ = dpp_wave_max_l63(m_); \
    const int wm_ = __builtin_amdgcn_readlane(__float_as_int(m_), 63); \
    const int e_ = (wm_ >> 23) & 0xFF; \
    const float sc_ = __int_as_float((254 - e_) << 23); \
    p0 *= sc_; p1 *= sc_; p2 *= sc_; p3 *= sc_; p4 *= sc_; \
    shift += e_ - 127; \
  }

  // consume reg + reissue it 8 rows ahead (no wait: grouped)
#define CR(R, O)  { COMPUTE(R); DSRO(R, O); }
  // tail (R20-verbatim): per-step waits, guarded
#define TS(R, O, i)  { WTL(R, 7); if (t0 + (i) < len) COMPUTE(R); DSRO(R, O); }
#define TD(R, N, i)  { WTL(R, N); if (t0 + (i) < len) COMPUTE(R); }

  int shift = 0;
  for (int c = 0; c < nch; ++c) {
    const int t0 = 1 + 32 * c;
    while (((volatile int*)flag_ready)[c & 1] < c + 1)
      __builtin_amdgcn_s_sleep(1);
    const unsigned vb = bufbase + (unsigned)(c & 1) * 32768u + (unsigned)l * 16u;

    DSRO(q0, 0);    DSRO(q1, 1024); DSRO(q2, 2048); DSRO(q3, 3072);
    DSRO(q4, 4096); DSRO(q5, 5120); DSRO(q6, 6144); DSRO(q7, 7168);

    if (t0 + 31 < len) {
      WAIT8;   // rows 0-7 ready
      CR(q0, 8192)  CR(q1, 9216)  CR(q2, 10240) CR(q3, 11264)
      CR(q4, 12288) CR(q5, 13312) CR(q6, 14336) CR(q7, 15360)
      WAIT8;   // rows 8-15 ready
      CR(q0, 16384) CR(q1, 17408) CR(q2, 18432) CR(q3, 19456)
      CR(q4, 20480) CR(q5, 21504) CR(q6, 22528) CR(q7, 23552)
      RENORM
      WAIT8;   // rows 16-23 ready
      CR(q0, 24576) CR(q1, 25600) CR(q2, 26624) CR(q3, 27648)
      CR(q4, 28672) CR(q5, 29696) CR(q6, 30720) CR(q7, 31744)
      WAIT8;   // rows 24-31 ready
      COMPUTE(q0) COMPUTE(q1) COMPUTE(q2) COMPUTE(q3)
      COMPUTE(q4) COMPUTE(q5) COMPUTE(q6) COMPUTE(q7)
      RENORM
    } else {
      TS(q0, 8192, 0)   TS(q1, 9216, 1)   TS(q2, 10240, 2)  TS(q3, 11264, 3)
      TS(q4, 12288, 4)  TS(q5, 13312, 5)  TS(q6, 14336, 6)  TS(q7, 15360, 7)
      TS(q0, 16384, 8)  TS(q1, 17408, 9)  TS(q2, 18432, 10) TS(q3, 19456, 11)
      TS(q4, 20480, 12) TS(q5, 21504, 13) TS(q6, 22528, 14) TS(q7, 23552, 15)
      TS(q0, 24576, 16) TS(q1, 25600, 17) TS(q2, 26624, 18) TS(q3, 27648, 19)
      TS(q4, 28672, 20) TS(q5, 29696, 21) TS(q6, 30720, 22) TS(q7, 31744, 23)
      TD(q0, 7, 24) TD(q1, 6, 25) TD(q2, 5, 26) TD(q3, 4, 27)
      TD(q4, 3, 28) TD(q5, 2, 29) TD(q6, 1, 30) TD(q7, 0, 31)
    }

    asm volatile("s_waitcnt lgkmcnt(0)" ::: "memory");
    if (l == 0) ((volatile int*)flag_done)[c & 1] = c + 1;
  }

  A[4 * l + 0] = p0; A[4 * l + 1] = p1;
  A[4 * l + 2] = p2; A[4 * l + 3] = p3;
  if (l == 63) A[256] = p4;
  asm volatile("s_waitcnt lgkmcnt(0)" ::: "memory");
  if (l == 0) {
    const int ib = 2 * tl;
    const int il = (ib - 1) > 0 ? ib - 1 : 0;
    const float ab = A[ib];
    const float al = (tl > 0) ? A[il] : 0.0f;
    out[b] = -(__builtin_log2f(ab + al) + (float)(shift - BOOSTI * len)) * LN2F;
  }
}

extern "C" void kernel_launch(void* const* d_in, const int* in_sizes, int n_in,
                              void* d_out, int out_size, void* d_ws, size_t ws_size,
                              hipStream_t stream) {
  const float* logits  = (const float*)d_in[0];
  const int*   targets = (const int*)d_in[1];
  const int*   loglen  = (const int*)d_in[2];
  const int*   tgtlen  = (const int*)d_in[3];
  float* out = (float*)d_out;
  f32x4* Q = (f32x4*)d_ws;   // 32 MiB (proven sufficient in R8-R20)

  ctc_pre4<<<(B_ * T_) / 4, 256, 0, stream>>>(logits, targets, loglen, tgtlen, Q);
  ctc_dp7<<<B_, 128, 0, stream>>>(Q, targets, loglen, tgtlen, out);
}